// Round 22
// baseline (129.836 us; speedup 1.0000x reference)
//
#include <hip/hip_runtime.h>
#include <hip/hip_bf16.h>

typedef __attribute__((ext_vector_type(8))) short s16x8;
typedef __attribute__((ext_vector_type(4))) short s16x4;
typedef __attribute__((ext_vector_type(4))) float f32x4;

#define SEQ 2048
#define NB 2
#define NH 16
#define HD 64
#define DIM 1024
#define MR (NB * SEQ)
#define NT (SEQ / 64)
#define QSC 0.18033688011112042f /* 0.125 * log2(e): folded into Q so p = exp2(s) */

__device__ __forceinline__ unsigned short f2b(float f) {
    unsigned u = __float_as_uint(f);
    u += 0x7fffu + ((u >> 16) & 1u);
    return (unsigned short)(u >> 16);
}

// single-instruction packed f32x2 -> bf16x2 (RNE), gfx950 native
__device__ __forceinline__ unsigned pk2(float a, float b) {
    unsigned r;
    asm("v_cvt_pk_bf16_f32 %0, %1, %2" : "=v"(r) : "v"(a), "v"(b));
    return r;
}

// bare v_exp_f32 (no ocml range/denormal fixup; args bounded |s|<~12)
__device__ __forceinline__ float fx2(float x) { return __builtin_amdgcn_exp2f(x); }

__device__ __forceinline__ s16x8 mk8(unsigned a, unsigned b, unsigned c, unsigned d) {
    union { unsigned u[4]; s16x8 v; } x;
    x.u[0] = a; x.u[1] = b; x.u[2] = c; x.u[3] = d;
    return x.v;
}

__device__ __forceinline__ s16x8 cat8(s16x4 a, s16x4 b) {
    union { s16x4 h[2]; s16x8 v; } x;
    x.h[0] = a; x.h[1] = b;
    return x.v;
}

// async global->LDS, 16B per lane; LDS dest = wave-uniform base + lane*16
__device__ __forceinline__ void gl_lds16(const unsigned short* g, unsigned short* l) {
    __builtin_amdgcn_global_load_lds(
        (const __attribute__((address_space(1))) void*)g,
        (__attribute__((address_space(3))) void*)l, 16, 0, 0);
}

// generic(shared) pointer -> 32-bit LDS byte offset for inline-asm DS ops
__device__ __forceinline__ unsigned ldsoff(const void* p) {
    return (unsigned)(size_t)(const __attribute__((address_space(3))) void*)p;
}

__device__ __forceinline__ void cast4(const float* __restrict__ src, unsigned short* __restrict__ dst, int i) {
    float4 v = reinterpret_cast<const float4*>(src)[i];
    ushort4 o;
    o.x = f2b(v.x); o.y = f2b(v.y); o.z = f2b(v.z); o.w = f2b(v.w);
    reinterpret_cast<ushort4*>(dst)[i] = o;
}

// One fused prep kernel: casts x,wq,wk,wv,wo to bf16 + builds RoPE cos/sin table.
__global__ __launch_bounds__(256) void prep_kernel(
    const float* __restrict__ x, const float* __restrict__ wq, const float* __restrict__ wk,
    const float* __restrict__ wv, const float* __restrict__ wo,
    unsigned short* __restrict__ xb, unsigned short* __restrict__ wqkv,
    unsigned short* __restrict__ wwo, float2* __restrict__ tab)
{
    int b = blockIdx.x, t = threadIdx.x;
    if (b < 4096)       cast4(x,  xb,                 b * 256 + t);
    else if (b < 5120)  cast4(wq, wqkv,               (b - 4096) * 256 + t);
    else if (b < 6144)  cast4(wk, wqkv + DIM * DIM,   (b - 5120) * 256 + t);
    else if (b < 7168)  cast4(wv, wqkv + 2 * DIM * DIM, (b - 6144) * 256 + t);
    else if (b < 8192)  cast4(wo, wwo,                (b - 7168) * 256 + t);
    else {
        int i = (b - 8192) * 256 + t; // 2048*32 = 65536
        int pos = i >> 5, fi = i & 31;
        float freq = expf((float)fi * (-9.210340371976184f / 32.0f)); // 10000^(-fi/32)
        float emb = (float)pos * freq;
        tab[i] = make_float2(cosf(emb), sinf(emb));
    }
}

// C = A * B^T ; A [M][1024] bf16 row-major, Bw [N][1024] bf16 row-major.
// MULTI-WAVE COUNTED-VMCNT GEMM, DEPTH-3 (r22): 128x128 tile, 4 waves, BK=32,
// TRIPLE-buffered (48KB LDS -> still 3 blocks/CU). Stage t is issued at iter
// t-3 and consumed at iter t (~2 K-steps of latency budget vs 1 at depth-2).
// Steady state: vmcnt(8) [stages t+1,t+2 flying] -> raw s_barrier -> ds_read
// -> lgkm(0) -> raw s_barrier -> STG(t+3) -> 16 MFMA. Never drains in-loop.
// A-resident stripe grid. EPI==0: RoPE Q,K (Q pre-scaled), V natural.
template <int EPI>
__global__ __launch_bounds__(256) void gemm_mw(
    const unsigned short* __restrict__ A,
    const unsigned short* __restrict__ Bw,
    const float2* __restrict__ tab,
    unsigned short* __restrict__ qw,
    unsigned short* __restrict__ kw,
    unsigned short* __restrict__ vw,
    float* __restrict__ out,
    const float* __restrict__ bias)
{
    __shared__ unsigned short As[3][4096];
    __shared__ unsigned short Bs[3][4096];
    const int t = threadIdx.x;
    const int wid = t >> 6, lane = t & 63;
    const int wr = wid >> 1, wc = wid & 1;
    const int lo = lane & 15, hi = lane >> 4;
    const int wg = blockIdx.x;
    const int xcd = wg & 7, bi = wg >> 3;
    const int by = xcd * 4 + (bi & 3);
    const int bx = bi >> 2;
    const int m0 = by * 128, n0 = bx * 128;

    const unsigned short* agp = A + (long)(m0 + (t >> 2)) * DIM + (t & 3) * 8;
    const unsigned short* bgp = Bw + (long)(n0 + (t >> 2)) * DIM + (t & 3) * 8;
    unsigned short* alds = &As[0][0] + wid * 512;
    unsigned short* blds = &Bs[0][0] + wid * 512;

#define STG(buf, k0) {                                        \
        gl_lds16(agp + (k0), alds + (buf) * 4096);            \
        gl_lds16(agp + (k0) + 64 * DIM, alds + (buf) * 4096 + 2048); \
        gl_lds16(bgp + (k0), blds + (buf) * 4096);            \
        gl_lds16(bgp + (k0) + 64 * DIM, blds + (buf) * 4096 + 2048); }

    f32x4 acc[4][4] = {};
    STG(0, 0)
    STG(1, 32)
    STG(2, 64)

    int cb = 0;
    for (int kt = 0; kt < 32; ++kt) {
        if (kt < 30)       { asm volatile("s_waitcnt vmcnt(8)" ::: "memory"); }
        else if (kt == 30) { asm volatile("s_waitcnt vmcnt(4)" ::: "memory"); }
        else               { asm volatile("s_waitcnt vmcnt(0)" ::: "memory"); }
        __builtin_amdgcn_sched_barrier(0);
        __builtin_amdgcn_s_barrier(); // everyone's stage for buf cb retired
        __builtin_amdgcn_sched_barrier(0);
        s16x8 af[4], bf[4];
#pragma unroll
        for (int i = 0; i < 4; ++i)
            af[i] = *reinterpret_cast<const s16x8*>(&As[cb][(wr * 64 + i * 16 + lo) * 32 + hi * 8]);
#pragma unroll
        for (int j = 0; j < 4; ++j)
            bf[j] = *reinterpret_cast<const s16x8*>(&Bs[cb][(wc * 64 + j * 16 + lo) * 32 + hi * 8]);
        asm volatile("s_waitcnt lgkmcnt(0)" ::: "memory"); // my frags in regs
        __builtin_amdgcn_sched_barrier(0);
        if (kt + 3 < 32) {
            __builtin_amdgcn_s_barrier(); // all waves read buf cb -> free to overwrite
            __builtin_amdgcn_sched_barrier(0);
            STG(cb, (kt + 3) * 32)
        }
        __builtin_amdgcn_s_setprio(1);
#pragma unroll
        for (int i = 0; i < 4; ++i)
#pragma unroll
            for (int j = 0; j < 4; ++j)
                acc[i][j] = __builtin_amdgcn_mfma_f32_16x16x32_bf16(af[i], bf[j], acc[i][j], 0, 0, 0);
        __builtin_amdgcn_s_setprio(0);
        cb = (cb == 2) ? 0 : cb + 1;
    }
#undef STG

    const int rowb = m0 + wr * 64;
    const int colb = n0 + wc * 64;
    if (EPI == 0) {
#pragma unroll
        for (int ai = 0; ai < 4; ++ai) {
#pragma unroll
            for (int cp = 0; cp < 2; ++cp) {
                f32x4 v1 = acc[ai][cp];
                f32x4 v2 = acc[ai][cp + 2];
                int e = colb + cp * 16 + lo;
                int which = e >> 10;
                int eh = e & 1023;
                int h = eh >> 6, d = eh & 63;
                unsigned short* dst = (which == 0) ? qw : ((which == 1) ? kw : vw);
                float qs = (which == 0) ? QSC : 1.0f;
#pragma unroll
                for (int r = 0; r < 4; ++r) {
                    int m = rowb + ai * 16 + hi * 4 + r;
                    int b = m >> 11, pos = m & (SEQ - 1);
                    long off = (((long)(b * NH + h)) * SEQ + pos) * HD;
                    if (which == 2) {
                        dst[off + d]      = f2b(v1[r]);
                        dst[off + d + 32] = f2b(v2[r]);
                    } else {
                        float2 cs = tab[pos * 32 + d];
                        dst[off + d]      = f2b((v1[r] * cs.x - v2[r] * cs.y) * qs);
                        dst[off + d + 32] = f2b((v1[r] * cs.y + v2[r] * cs.x) * qs);
                    }
                }
            }
        }
    } else {
#pragma unroll
        for (int ai = 0; ai < 4; ++ai)
#pragma unroll
            for (int cj = 0; cj < 4; ++cj) {
                int n = colb + cj * 16 + lo;
                float bv = bias[n];
#pragma unroll
                for (int r = 0; r < 4; ++r) {
                    int m = rowb + ai * 16 + hi * 4 + r;
                    out[(long)m * DIM + n] = acc[ai][cj][r] + bv;
                }
            }
    }
}

// 1-WAVE barrier-free GEMM (r14): 64x128 per wave, private dbuf LDS, counted
// vmcnt(12) depth-2, zero barriers. Used for the out-projection (small grid).
template <int EPI>
__global__ __launch_bounds__(64, 2) void gemm_async(
    const unsigned short* __restrict__ A,
    const unsigned short* __restrict__ Bw,
    const float2* __restrict__ tab,
    unsigned short* __restrict__ qw,
    unsigned short* __restrict__ kw,
    unsigned short* __restrict__ vw,
    float* __restrict__ out,
    const float* __restrict__ bias)
{
    __shared__ unsigned short As[2 * 2048];
    __shared__ unsigned short Bs[2 * 4096];
    const int lane = threadIdx.x & 63;
    const int lo = lane & 15, hi = lane >> 4;
    const int wg = blockIdx.x;
    const int xcd = wg & 7, bi = wg >> 3;
    const int bx = bi >> 3;
    const int by = xcd * 8 + (bi & 7);
    const int m0 = by * 64, n0 = bx * 128;

    const unsigned short* agp = A + (long)(m0 + (lane >> 2)) * DIM + (lane & 3) * 8;
    const unsigned short* bgp = Bw + (long)(n0 + (lane >> 2)) * DIM + (lane & 3) * 8;

    f32x4 acc[4][8] = {};

#define STG(buf, k0) {                                       \
        unsigned short* al = &As[(buf) * 2048];              \
        unsigned short* bl = &Bs[(buf) * 4096];              \
        _Pragma("unroll") for (int s = 0; s < 4; ++s)        \
            gl_lds16(agp + (k0) + (long)s * 16 * DIM, al + s * 512); \
        _Pragma("unroll") for (int s = 0; s < 8; ++s)        \
            gl_lds16(bgp + (k0) + (long)s * 16 * DIM, bl + s * 512); }

    STG(0, 0)
    STG(1, 32)

    for (int kt = 0; kt < 32; ++kt) {
        const int cb = kt & 1;
        if (kt < 31) { asm volatile("s_waitcnt vmcnt(12)" ::: "memory"); }
        else         { asm volatile("s_waitcnt vmcnt(0)" ::: "memory"); }
        __builtin_amdgcn_sched_barrier(0);
        s16x8 af[4], bf[8];
#pragma unroll
        for (int i = 0; i < 4; ++i)
            af[i] = *reinterpret_cast<const s16x8*>(&As[cb * 2048 + (i * 16 + lo) * 32 + hi * 8]);
#pragma unroll
        for (int j = 0; j < 8; ++j)
            bf[j] = *reinterpret_cast<const s16x8*>(&Bs[cb * 4096 + (j * 16 + lo) * 32 + hi * 8]);
        asm volatile("s_waitcnt lgkmcnt(0)" ::: "memory");
        __builtin_amdgcn_sched_barrier(0);
        if (kt + 2 < 32) STG(cb, (kt + 2) * 32)
        __builtin_amdgcn_sched_barrier(0);
        __builtin_amdgcn_s_setprio(1);
#pragma unroll
        for (int i = 0; i < 4; ++i)
#pragma unroll
            for (int j = 0; j < 8; ++j)
                acc[i][j] = __builtin_amdgcn_mfma_f32_16x16x32_bf16(af[i], bf[j], acc[i][j], 0, 0, 0);
        __builtin_amdgcn_s_setprio(0);
    }
#undef STG

    if (EPI == 1) {
#pragma unroll
        for (int ai = 0; ai < 4; ++ai)
#pragma unroll
            for (int bj = 0; bj < 8; ++bj) {
                int n = n0 + bj * 16 + lo;
                float bv = bias[n];
#pragma unroll
                for (int r = 0; r < 4; ++r) {
                    int m = m0 + ai * 16 + hi * 4 + r;
                    out[(long)m * DIM + n] = acc[ai][bj][r] + bv;
                }
            }
    }
}

// Flash attention (r21 champion): k-split waves, wave-private KV, no main-loop
// barriers, depth-2 gl_lds + counted vmcnt, XCD swizzle, 2-tile mega-iterations
// with PV batched at K=32, V via ds_read_b64_tr_b16, unnormalized softmax,
// bare v_exp_f32.
__global__ __launch_bounds__(256) void flash_attn(
    const unsigned short* __restrict__ qw,
    const unsigned short* __restrict__ kw,
    const unsigned short* __restrict__ vw,
    unsigned short* __restrict__ ao)
{
    __shared__ __align__(16) unsigned char smem[33792];
    const int t = threadIdx.x;
    const int w = t >> 6, lane = t & 63;
    const int lo = lane & 15, hi = lane >> 4;
    const int wg = blockIdx.x;
    const int swz = (wg & 7) * 128 + (wg >> 3);
    const int bh = swz >> 5;
    const int q0 = (swz & 31) * 64;
    const unsigned short* qh = qw + (long)bh * SEQ * HD;
    const unsigned short* kh = kw + (long)bh * SEQ * HD;
    const unsigned short* vh = vw + (long)bh * SEQ * HD;

    s16x8 qf[4][2];
#pragma unroll
    for (int qt = 0; qt < 4; ++qt)
#pragma unroll
        for (int ds = 0; ds < 2; ++ds)
            qf[qt][ds] = *reinterpret_cast<const s16x8*>(
                qh + (long)(q0 + qt * 16 + lo) * HD + ds * 32 + hi * 8);
    asm volatile("s_waitcnt vmcnt(0)" ::: "memory");

    unsigned char* wbase = smem + w * 8192;
    const int kr0 = lane >> 3, ks0 = (lane & 7) ^ (kr0 & 7);
    const int kr1 = 8 + (lane >> 3), ks1 = (lane & 7) ^ (kr1 & 7);
    const unsigned short* ksrc0 = kh + (16 * w + kr0) * HD + ks0 * 8;
    const unsigned short* ksrc1 = kh + (16 * w + kr1) * HD + ks1 * 8;
    const int c0 = lane, c1 = 64 + lane;
    const int kl0 = ((c0 >> 3 >> 2) << 2) | ((c0 >> 1) & 3);
    const int dd0 = (((c0 >> 3) & 3) << 4) | ((c0 & 1) << 3);
    const int kl1 = ((c1 >> 3 >> 2) << 2) | ((c1 >> 1) & 3);
    const int dd1 = (((c1 >> 3) & 3) << 4) | ((c1 & 1) << 3);
    const unsigned short* vsrc0 = vh + (16 * w + kl0) * HD + dd0;
    const unsigned short* vsrc1 = vh + (16 * w + kl1) * HD + dd1;

#define STAGE(buf, kb) {                                              \
        unsigned short* d_ = (unsigned short*)(wbase + (buf) * 4096); \
        gl_lds16(ksrc0 + (kb) * HD, d_);                              \
        gl_lds16(ksrc1 + (kb) * HD, d_ + 512);                        \
        gl_lds16(vsrc0 + (kb) * HD, d_ + 1024);                       \
        gl_lds16(vsrc1 + (kb) * HD, d_ + 1536); }

    const int kro0 = lo * 128 + ((hi ^ (lo & 7)) << 4);
    const int kro1 = lo * 128 + (((4 + hi) ^ (lo & 7)) << 4);
    const unsigned vtb0 = ldsoff(wbase) + 2048 + hi * 512 + lo * 8;

    f32x4 od[4][4] = {};
    f32x4 lr = {0.f, 0.f, 0.f, 0.f};

    STAGE(0, 0)
    STAGE(1, 64)

    constexpr int NT2 = NT / 2;
    for (int i2 = 0; i2 < NT2; ++i2) {
        const bool more = (i2 + 1 < NT2);
        asm volatile("s_waitcnt vmcnt(4)" ::: "memory");
        s16x8 kf0 = *reinterpret_cast<const s16x8*>(wbase + kro0);
        s16x8 kf1 = *reinterpret_cast<const s16x8*>(wbase + kro1);
        s16x4 va0, va1, va2, va3;
        asm volatile("ds_read_b64_tr_b16 %0, %1"            : "=v"(va0) : "v"(vtb0));
        asm volatile("ds_read_b64_tr_b16 %0, %1 offset:128" : "=v"(va1) : "v"(vtb0));
        asm volatile("ds_read_b64_tr_b16 %0, %1 offset:256" : "=v"(va2) : "v"(vtb0));
        asm volatile("ds_read_b64_tr_b16 %0, %1 offset:384" : "=v"(va3) : "v"(vtb0));
        asm volatile("s_waitcnt lgkmcnt(0)" ::: "memory");
        __builtin_amdgcn_sched_barrier(0);

        f32x4 sc[4] = {};
        __builtin_amdgcn_s_setprio(1);
#pragma unroll
        for (int qt = 0; qt < 4; ++qt)
            sc[qt] = __builtin_amdgcn_mfma_f32_16x16x32_bf16(kf0, qf[qt][0], sc[qt], 0, 0, 0);
#pragma unroll
        for (int qt = 0; qt < 4; ++qt)
            sc[qt] = __builtin_amdgcn_mfma_f32_16x16x32_bf16(kf1, qf[qt][1], sc[qt], 0, 0, 0);
        __builtin_amdgcn_s_setprio(0);
        if (more) STAGE(0, (2 * i2 + 2) * 64)

        unsigned u01[4], u23[4];
#pragma unroll
        for (int qt = 0; qt < 4; ++qt) {
            float p0 = fx2(sc[qt][0]), p1 = fx2(sc[qt][1]);
            float p2 = fx2(sc[qt][2]), p3 = fx2(sc[qt][3]);
            lr[qt] += (p0 + p1) + (p2 + p3);
            u01[qt] = pk2(p0, p1); u23[qt] = pk2(p2, p3);
        }

        if (more) { asm volatile("s_waitcnt vmcnt(4)" ::: "memory"); }
        else      { asm volatile("s_waitcnt vmcnt(0)" ::: "memory"); }
        s16x8 kg0 = *reinterpret_cast<const s16x8*>(wbase + 4096 + kro0);
        s16x8 kg1 = *reinterpret_cast<const s16x8*>(wbase + 4096 + kro1);
        s16x4 vb0, vb1, vb2, vb3;
        const unsigned vtb1 = vtb0 + 4096;
        asm volatile("ds_read_b64_tr_b16 %0, %1"            : "=v"(vb0) : "v"(vtb1));
        asm volatile("ds_read_b64_tr_b16 %0, %1 offset:128" : "=v"(vb1) : "v"(vtb1));
        asm volatile("ds_read_b64_tr_b16 %0, %1 offset:256" : "=v"(vb2) : "v"(vtb1));
        asm volatile("ds_read_b64_tr_b16 %0, %1 offset:384" : "=v"(vb3) : "v"(vtb1));
        asm volatile("s_waitcnt lgkmcnt(0)" ::: "memory");
        __builtin_amdgcn_sched_barrier(0);

        f32x4 sd[4] = {};
        __builtin_amdgcn_s_setprio(1);
#pragma unroll
        for (int qt = 0; qt < 4; ++qt)
            sd[qt] = __builtin_amdgcn_mfma_f32_16x16x32_bf16(kg0, qf[qt][0], sd[qt], 0, 0, 0);
#pragma unroll
        for (int qt = 0; qt < 4; ++qt)
            sd[qt] = __builtin_amdgcn_mfma_f32_16x16x32_bf16(kg1, qf[qt][1], sd[qt], 0, 0, 0);
        __builtin_amdgcn_s_setprio(0);
        if (more) STAGE(1, (2 * i2 + 3) * 64)

        s16x8 pf8[4];
#pragma unroll
        for (int qt = 0; qt < 4; ++qt) {
            float p0 = fx2(sd[qt][0]), p1 = fx2(sd[qt][1]);
            float p2 = fx2(sd[qt][2]), p3 = fx2(sd[qt][3]);
            lr[qt] += (p0 + p1) + (p2 + p3);
            pf8[qt] = mk8(u01[qt], u23[qt], pk2(p0, p1), pk2(p2, p3));
        }
        s16x8 vf80 = cat8(va0, vb0), vf81 = cat8(va1, vb1);
        s16x8 vf82 = cat8(va2, vb2), vf83 = cat8(va3, vb3);

        __builtin_amdgcn_s_setprio(1);
#pragma unroll
        for (int qt = 0; qt < 4; ++qt) {
            od[0][qt] = __builtin_amdgcn_mfma_f32_16x16x32_bf16(vf80, pf8[qt], od[0][qt], 0, 0, 0);
            od[1][qt] = __builtin_amdgcn_mfma_f32_16x16x32_bf16(vf81, pf8[qt], od[1][qt], 0, 0, 0);
            od[2][qt] = __builtin_amdgcn_mfma_f32_16x16x32_bf16(vf82, pf8[qt], od[2][qt], 0, 0, 0);
            od[3][qt] = __builtin_amdgcn_mfma_f32_16x16x32_bf16(vf83, pf8[qt], od[3][qt], 0, 0, 0);
        }
        __builtin_amdgcn_s_setprio(0);
    }
#undef STAGE

#pragma unroll
    for (int qt = 0; qt < 4; ++qt) {
        lr[qt] += __shfl_xor(lr[qt], 16);
        lr[qt] += __shfl_xor(lr[qt], 32);
    }
    __syncthreads();
    float* red = reinterpret_cast<float*>(smem);
    float* ldl = reinterpret_cast<float*>(smem + 32768);
    if (lane < 16) {
#pragma unroll
        for (int qt = 0; qt < 4; ++qt) ldl[w * 64 + qt * 16 + lane] = lr[qt];
    }

    const int b = bh >> 4, h = bh & 15;
    const int ql = w * 16 + (lane >> 2);
    const int qc = ql & 7;
    float linv = 0.f;
#pragma unroll
    for (int p = 0; p < 2; ++p) {
        if (p) __syncthreads();
#pragma unroll
        for (int dtp = 0; dtp < 2; ++dtp) {
#pragma unroll
            for (int qt = 0; qt < 4; ++qt) {
                int q = qt * 16 + lo;
                int quad = ((dtp << 2) + hi) ^ (lo & 7);
                *reinterpret_cast<f32x4*>(red + w * 2048 + q * 32 + quad * 4) = od[p * 2 + dtp][qt];
            }
        }
        __syncthreads();
        float s0[8] = {0.f, 0.f, 0.f, 0.f, 0.f, 0.f, 0.f, 0.f};
#pragma unroll
        for (int w2 = 0; w2 < 4; ++w2)
#pragma unroll
            for (int k = 0; k < 2; ++k) {
                int quad = (((lane & 3) << 1) + k) ^ qc;
                f32x4 v = *reinterpret_cast<const f32x4*>(red + w2 * 2048 + ql * 32 + quad * 4);
#pragma unroll
                for (int j = 0; j < 4; ++j) s0[k * 4 + j] += v[j];
            }
        if (p == 0)
            linv = 1.f / (ldl[ql] + ldl[64 + ql] + ldl[128 + ql] + ldl[192 + ql]);
        unsigned uu[4];
#pragma unroll
        for (int k2 = 0; k2 < 4; ++k2)
            uu[k2] = pk2(s0[2 * k2] * linv, s0[2 * k2 + 1] * linv);
        int4 ov;
        ov.x = uu[0]; ov.y = uu[1]; ov.z = uu[2]; ov.w = uu[3];
        *reinterpret_cast<int4*>(ao + ((long)(b * SEQ + q0 + ql)) * DIM +
                                 h * 64 + p * 32 + (lane & 3) * 8) = ov;
    }
}

extern "C" void kernel_launch(void* const* d_in, const int* in_sizes, int n_in,
                              void* d_out, int out_size, void* d_ws, size_t ws_size,
                              hipStream_t stream) {
    const float* x   = (const float*)d_in[0];
    const float* wq  = (const float*)d_in[1];
    const float* wk  = (const float*)d_in[2];
    const float* wv  = (const float*)d_in[3];
    const float* wo  = (const float*)d_in[4];
    const float* wob = (const float*)d_in[5];

    char* ws = (char*)d_ws;
    unsigned short* xb   = (unsigned short*)(ws);             // 8.0 MiB
    unsigned short* wqkv = (unsigned short*)(ws + 8388608);   // 6.0 MiB
    unsigned short* wwo  = (unsigned short*)(ws + 14680064);  // 2.0 MiB
    unsigned short* qw   = (unsigned short*)(ws + 16777216);  // 8.0 MiB
    unsigned short* kw   = (unsigned short*)(ws + 25165824);  // 8.0 MiB
    unsigned short* vw   = (unsigned short*)(ws + 33554432);  // 8.0 MiB
    unsigned short* ao   = (unsigned short*)(ws + 41943040);  // 8.0 MiB
    float2* tab          = (float2*)(ws + 50331648);          // 512 KiB

    prep_kernel<<<8448, 256, 0, stream>>>(x, wq, wk, wv, wo, xb, wqkv, wwo, tab);

    // gemm0: 24 x-tiles x 32 y-tiles (128x128) = 768 multi-wave blocks
    gemm_mw<0><<<768, 256, 0, stream>>>(xb, wqkv, tab, qw, kw, vw, nullptr, nullptr);
    flash_attn<<<1024, 256, 0, stream>>>(qw, kw, vw, ao);
    // gemm1: 8 x-tiles x 64 y-tiles = 512 one-wave blocks (r14)
    gemm_async<1><<<512, 64, 0, stream>>>(ao, wwo, nullptr, nullptr, nullptr, nullptr,
                                          (float*)d_out, wob);
}

// Round 23
// 119.068 us; speedup vs baseline: 1.0904x; 1.0904x over previous
//
#include <hip/hip_runtime.h>
#include <hip/hip_bf16.h>

typedef __attribute__((ext_vector_type(8))) short s16x8;
typedef __attribute__((ext_vector_type(4))) short s16x4;
typedef __attribute__((ext_vector_type(4))) float f32x4;

#define SEQ 2048
#define NB 2
#define NH 16
#define HD 64
#define DIM 1024
#define MR (NB * SEQ)
#define NT (SEQ / 64)
#define QSC 0.18033688011112042f /* 0.125 * log2(e): folded into Q so p = exp2(s) */

__device__ __forceinline__ unsigned short f2b(float f) {
    unsigned u = __float_as_uint(f);
    u += 0x7fffu + ((u >> 16) & 1u);
    return (unsigned short)(u >> 16);
}

// single-instruction packed f32x2 -> bf16x2 (RNE), gfx950 native
__device__ __forceinline__ unsigned pk2(float a, float b) {
    unsigned r;
    asm("v_cvt_pk_bf16_f32 %0, %1, %2" : "=v"(r) : "v"(a), "v"(b));
    return r;
}

// bare v_exp_f32 (no ocml range/denormal fixup; args bounded |s|<~12)
__device__ __forceinline__ float fx2(float x) { return __builtin_amdgcn_exp2f(x); }

__device__ __forceinline__ s16x8 mk8(unsigned a, unsigned b, unsigned c, unsigned d) {
    union { unsigned u[4]; s16x8 v; } x;
    x.u[0] = a; x.u[1] = b; x.u[2] = c; x.u[3] = d;
    return x.v;
}

__device__ __forceinline__ s16x8 cat8(s16x4 a, s16x4 b) {
    union { s16x4 h[2]; s16x8 v; } x;
    x.h[0] = a; x.h[1] = b;
    return x.v;
}

// async global->LDS, 16B per lane; LDS dest = wave-uniform base + lane*16
__device__ __forceinline__ void gl_lds16(const unsigned short* g, unsigned short* l) {
    __builtin_amdgcn_global_load_lds(
        (const __attribute__((address_space(1))) void*)g,
        (__attribute__((address_space(3))) void*)l, 16, 0, 0);
}

// generic(shared) pointer -> 32-bit LDS byte offset for inline-asm DS ops
__device__ __forceinline__ unsigned ldsoff(const void* p) {
    return (unsigned)(size_t)(const __attribute__((address_space(3))) void*)p;
}

__device__ __forceinline__ void cast4(const float* __restrict__ src, unsigned short* __restrict__ dst, int i) {
    float4 v = reinterpret_cast<const float4*>(src)[i];
    ushort4 o;
    o.x = f2b(v.x); o.y = f2b(v.y); o.z = f2b(v.z); o.w = f2b(v.w);
    reinterpret_cast<ushort4*>(dst)[i] = o;
}

// One fused prep kernel: casts x,wq,wk,wv,wo to bf16 + builds RoPE cos/sin table.
__global__ __launch_bounds__(256) void prep_kernel(
    const float* __restrict__ x, const float* __restrict__ wq, const float* __restrict__ wk,
    const float* __restrict__ wv, const float* __restrict__ wo,
    unsigned short* __restrict__ xb, unsigned short* __restrict__ wqkv,
    unsigned short* __restrict__ wwo, float2* __restrict__ tab)
{
    int b = blockIdx.x, t = threadIdx.x;
    if (b < 4096)       cast4(x,  xb,                 b * 256 + t);
    else if (b < 5120)  cast4(wq, wqkv,               (b - 4096) * 256 + t);
    else if (b < 6144)  cast4(wk, wqkv + DIM * DIM,   (b - 5120) * 256 + t);
    else if (b < 7168)  cast4(wv, wqkv + 2 * DIM * DIM, (b - 6144) * 256 + t);
    else if (b < 8192)  cast4(wo, wwo,                (b - 7168) * 256 + t);
    else {
        int i = (b - 8192) * 256 + t; // 2048*32 = 65536
        int pos = i >> 5, fi = i & 31;
        float freq = expf((float)fi * (-9.210340371976184f / 32.0f)); // 10000^(-fi/32)
        float emb = (float)pos * freq;
        tab[i] = make_float2(cosf(emb), sinf(emb));
    }
}

// C = A * B^T ; A [M][1024] bf16 row-major, Bw [N][1024] bf16 row-major.
// MULTI-WAVE COUNTED-VMCNT GEMM (proven optimum): 128x128 tile, 4 waves,
// BK=32 DEPTH-2 dbuf (depth-3 regressed: runtime buffer index defeats
// compile-time LDS addressing). vmcnt(4) -> raw s_barrier -> ds_read ->
// lgkm(0) -> raw s_barrier -> STG(t+2) -> 16 MFMA; never drains in-loop.
// A-resident stripe grid. EPI==0: RoPE Q,K (Q pre-scaled), V natural.
template <int EPI>
__global__ __launch_bounds__(256) void gemm_mw(
    const unsigned short* __restrict__ A,
    const unsigned short* __restrict__ Bw,
    const float2* __restrict__ tab,
    unsigned short* __restrict__ qw,
    unsigned short* __restrict__ kw,
    unsigned short* __restrict__ vw,
    float* __restrict__ out,
    const float* __restrict__ bias)
{
    __shared__ unsigned short As[2][4096];
    __shared__ unsigned short Bs[2][4096];
    const int t = threadIdx.x;
    const int wid = t >> 6, lane = t & 63;
    const int wr = wid >> 1, wc = wid & 1;
    const int lo = lane & 15, hi = lane >> 4;
    const int wg = blockIdx.x;
    const int xcd = wg & 7, bi = wg >> 3;
    const int by = xcd * 4 + (bi & 3);
    const int bx = bi >> 2;
    const int m0 = by * 128, n0 = bx * 128;

    const unsigned short* agp = A + (long)(m0 + (t >> 2)) * DIM + (t & 3) * 8;
    const unsigned short* bgp = Bw + (long)(n0 + (t >> 2)) * DIM + (t & 3) * 8;
    unsigned short* alds = &As[0][0] + wid * 512;
    unsigned short* blds = &Bs[0][0] + wid * 512;

#define STG(buf, k0) {                                        \
        gl_lds16(agp + (k0), alds + (buf) * 4096);            \
        gl_lds16(agp + (k0) + 64 * DIM, alds + (buf) * 4096 + 2048); \
        gl_lds16(bgp + (k0), blds + (buf) * 4096);            \
        gl_lds16(bgp + (k0) + 64 * DIM, blds + (buf) * 4096 + 2048); }

    f32x4 acc[4][4] = {};
    STG(0, 0)
    STG(1, 32)

    for (int kt = 0; kt < 32; ++kt) {
        const int cb = kt & 1;
        if (kt < 31) { asm volatile("s_waitcnt vmcnt(4)" ::: "memory"); }
        else         { asm volatile("s_waitcnt vmcnt(0)" ::: "memory"); }
        __builtin_amdgcn_sched_barrier(0);
        __builtin_amdgcn_s_barrier(); // everyone's stage for buf cb retired
        __builtin_amdgcn_sched_barrier(0);
        s16x8 af[4], bf[4];
#pragma unroll
        for (int i = 0; i < 4; ++i)
            af[i] = *reinterpret_cast<const s16x8*>(&As[cb][(wr * 64 + i * 16 + lo) * 32 + hi * 8]);
#pragma unroll
        for (int j = 0; j < 4; ++j)
            bf[j] = *reinterpret_cast<const s16x8*>(&Bs[cb][(wc * 64 + j * 16 + lo) * 32 + hi * 8]);
        asm volatile("s_waitcnt lgkmcnt(0)" ::: "memory"); // my frags in regs
        __builtin_amdgcn_sched_barrier(0);
        if (kt + 2 < 32) {
            __builtin_amdgcn_s_barrier(); // all waves read buf cb -> free to overwrite
            __builtin_amdgcn_sched_barrier(0);
            STG(cb, (kt + 2) * 32)
        }
        __builtin_amdgcn_s_setprio(1);
#pragma unroll
        for (int i = 0; i < 4; ++i)
#pragma unroll
            for (int j = 0; j < 4; ++j)
                acc[i][j] = __builtin_amdgcn_mfma_f32_16x16x32_bf16(af[i], bf[j], acc[i][j], 0, 0, 0);
        __builtin_amdgcn_s_setprio(0);
    }
#undef STG

    const int rowb = m0 + wr * 64;
    const int colb = n0 + wc * 64;
    if (EPI == 0) {
#pragma unroll
        for (int ai = 0; ai < 4; ++ai) {
#pragma unroll
            for (int cp = 0; cp < 2; ++cp) {
                f32x4 v1 = acc[ai][cp];
                f32x4 v2 = acc[ai][cp + 2];
                int e = colb + cp * 16 + lo;
                int which = e >> 10;
                int eh = e & 1023;
                int h = eh >> 6, d = eh & 63;
                unsigned short* dst = (which == 0) ? qw : ((which == 1) ? kw : vw);
                float qs = (which == 0) ? QSC : 1.0f;
#pragma unroll
                for (int r = 0; r < 4; ++r) {
                    int m = rowb + ai * 16 + hi * 4 + r;
                    int b = m >> 11, pos = m & (SEQ - 1);
                    long off = (((long)(b * NH + h)) * SEQ + pos) * HD;
                    if (which == 2) {
                        dst[off + d]      = f2b(v1[r]);
                        dst[off + d + 32] = f2b(v2[r]);
                    } else {
                        float2 cs = tab[pos * 32 + d];
                        dst[off + d]      = f2b((v1[r] * cs.x - v2[r] * cs.y) * qs);
                        dst[off + d + 32] = f2b((v1[r] * cs.y + v2[r] * cs.x) * qs);
                    }
                }
            }
        }
    } else {
#pragma unroll
        for (int ai = 0; ai < 4; ++ai)
#pragma unroll
            for (int cj = 0; cj < 4; ++cj) {
                int n = colb + cj * 16 + lo;
                float bv = bias[n];
#pragma unroll
                for (int r = 0; r < 4; ++r) {
                    int m = rowb + ai * 16 + hi * 4 + r;
                    out[(long)m * DIM + n] = acc[ai][cj][r] + bv;
                }
            }
    }
}

// 1-WAVE barrier-free GEMM (r14): 64x128 per wave, private dbuf LDS, counted
// vmcnt(12) depth-2, zero barriers. Used for the out-projection (small grid).
template <int EPI>
__global__ __launch_bounds__(64, 2) void gemm_async(
    const unsigned short* __restrict__ A,
    const unsigned short* __restrict__ Bw,
    const float2* __restrict__ tab,
    unsigned short* __restrict__ qw,
    unsigned short* __restrict__ kw,
    unsigned short* __restrict__ vw,
    float* __restrict__ out,
    const float* __restrict__ bias)
{
    __shared__ unsigned short As[2 * 2048];
    __shared__ unsigned short Bs[2 * 4096];
    const int lane = threadIdx.x & 63;
    const int lo = lane & 15, hi = lane >> 4;
    const int wg = blockIdx.x;
    const int xcd = wg & 7, bi = wg >> 3;
    const int bx = bi >> 3;
    const int by = xcd * 8 + (bi & 7);
    const int m0 = by * 64, n0 = bx * 128;

    const unsigned short* agp = A + (long)(m0 + (lane >> 2)) * DIM + (lane & 3) * 8;
    const unsigned short* bgp = Bw + (long)(n0 + (lane >> 2)) * DIM + (lane & 3) * 8;

    f32x4 acc[4][8] = {};

#define STG(buf, k0) {                                       \
        unsigned short* al = &As[(buf) * 2048];              \
        unsigned short* bl = &Bs[(buf) * 4096];              \
        _Pragma("unroll") for (int s = 0; s < 4; ++s)        \
            gl_lds16(agp + (k0) + (long)s * 16 * DIM, al + s * 512); \
        _Pragma("unroll") for (int s = 0; s < 8; ++s)        \
            gl_lds16(bgp + (k0) + (long)s * 16 * DIM, bl + s * 512); }

    STG(0, 0)
    STG(1, 32)

    for (int kt = 0; kt < 32; ++kt) {
        const int cb = kt & 1;
        if (kt < 31) { asm volatile("s_waitcnt vmcnt(12)" ::: "memory"); }
        else         { asm volatile("s_waitcnt vmcnt(0)" ::: "memory"); }
        __builtin_amdgcn_sched_barrier(0);
        s16x8 af[4], bf[8];
#pragma unroll
        for (int i = 0; i < 4; ++i)
            af[i] = *reinterpret_cast<const s16x8*>(&As[cb * 2048 + (i * 16 + lo) * 32 + hi * 8]);
#pragma unroll
        for (int j = 0; j < 8; ++j)
            bf[j] = *reinterpret_cast<const s16x8*>(&Bs[cb * 4096 + (j * 16 + lo) * 32 + hi * 8]);
        asm volatile("s_waitcnt lgkmcnt(0)" ::: "memory");
        __builtin_amdgcn_sched_barrier(0);
        if (kt + 2 < 32) STG(cb, (kt + 2) * 32)
        __builtin_amdgcn_sched_barrier(0);
        __builtin_amdgcn_s_setprio(1);
#pragma unroll
        for (int i = 0; i < 4; ++i)
#pragma unroll
            for (int j = 0; j < 8; ++j)
                acc[i][j] = __builtin_amdgcn_mfma_f32_16x16x32_bf16(af[i], bf[j], acc[i][j], 0, 0, 0);
        __builtin_amdgcn_s_setprio(0);
    }
#undef STG

    if (EPI == 1) {
#pragma unroll
        for (int ai = 0; ai < 4; ++ai)
#pragma unroll
            for (int bj = 0; bj < 8; ++bj) {
                int n = n0 + bj * 16 + lo;
                float bv = bias[n];
#pragma unroll
                for (int r = 0; r < 4; ++r) {
                    int m = m0 + ai * 16 + hi * 4 + r;
                    out[(long)m * DIM + n] = acc[ai][bj][r] + bv;
                }
            }
    }
}

// Flash attention (r21 champion): k-split waves, wave-private KV, no main-loop
// barriers, depth-2 gl_lds + counted vmcnt, XCD swizzle, 2-tile mega-iterations
// with PV batched at K=32, V via ds_read_b64_tr_b16, unnormalized softmax,
// bare v_exp_f32.
__global__ __launch_bounds__(256) void flash_attn(
    const unsigned short* __restrict__ qw,
    const unsigned short* __restrict__ kw,
    const unsigned short* __restrict__ vw,
    unsigned short* __restrict__ ao)
{
    __shared__ __align__(16) unsigned char smem[33792];
    const int t = threadIdx.x;
    const int w = t >> 6, lane = t & 63;
    const int lo = lane & 15, hi = lane >> 4;
    const int wg = blockIdx.x;
    const int swz = (wg & 7) * 128 + (wg >> 3);
    const int bh = swz >> 5;
    const int q0 = (swz & 31) * 64;
    const unsigned short* qh = qw + (long)bh * SEQ * HD;
    const unsigned short* kh = kw + (long)bh * SEQ * HD;
    const unsigned short* vh = vw + (long)bh * SEQ * HD;

    s16x8 qf[4][2];
#pragma unroll
    for (int qt = 0; qt < 4; ++qt)
#pragma unroll
        for (int ds = 0; ds < 2; ++ds)
            qf[qt][ds] = *reinterpret_cast<const s16x8*>(
                qh + (long)(q0 + qt * 16 + lo) * HD + ds * 32 + hi * 8);
    asm volatile("s_waitcnt vmcnt(0)" ::: "memory");

    unsigned char* wbase = smem + w * 8192;
    const int kr0 = lane >> 3, ks0 = (lane & 7) ^ (kr0 & 7);
    const int kr1 = 8 + (lane >> 3), ks1 = (lane & 7) ^ (kr1 & 7);
    const unsigned short* ksrc0 = kh + (16 * w + kr0) * HD + ks0 * 8;
    const unsigned short* ksrc1 = kh + (16 * w + kr1) * HD + ks1 * 8;
    const int c0 = lane, c1 = 64 + lane;
    const int kl0 = ((c0 >> 3 >> 2) << 2) | ((c0 >> 1) & 3);
    const int dd0 = (((c0 >> 3) & 3) << 4) | ((c0 & 1) << 3);
    const int kl1 = ((c1 >> 3 >> 2) << 2) | ((c1 >> 1) & 3);
    const int dd1 = (((c1 >> 3) & 3) << 4) | ((c1 & 1) << 3);
    const unsigned short* vsrc0 = vh + (16 * w + kl0) * HD + dd0;
    const unsigned short* vsrc1 = vh + (16 * w + kl1) * HD + dd1;

#define STAGE(buf, kb) {                                              \
        unsigned short* d_ = (unsigned short*)(wbase + (buf) * 4096); \
        gl_lds16(ksrc0 + (kb) * HD, d_);                              \
        gl_lds16(ksrc1 + (kb) * HD, d_ + 512);                        \
        gl_lds16(vsrc0 + (kb) * HD, d_ + 1024);                       \
        gl_lds16(vsrc1 + (kb) * HD, d_ + 1536); }

    const int kro0 = lo * 128 + ((hi ^ (lo & 7)) << 4);
    const int kro1 = lo * 128 + (((4 + hi) ^ (lo & 7)) << 4);
    const unsigned vtb0 = ldsoff(wbase) + 2048 + hi * 512 + lo * 8;

    f32x4 od[4][4] = {};
    f32x4 lr = {0.f, 0.f, 0.f, 0.f};

    STAGE(0, 0)
    STAGE(1, 64)

    constexpr int NT2 = NT / 2;
    for (int i2 = 0; i2 < NT2; ++i2) {
        const bool more = (i2 + 1 < NT2);
        asm volatile("s_waitcnt vmcnt(4)" ::: "memory");
        s16x8 kf0 = *reinterpret_cast<const s16x8*>(wbase + kro0);
        s16x8 kf1 = *reinterpret_cast<const s16x8*>(wbase + kro1);
        s16x4 va0, va1, va2, va3;
        asm volatile("ds_read_b64_tr_b16 %0, %1"            : "=v"(va0) : "v"(vtb0));
        asm volatile("ds_read_b64_tr_b16 %0, %1 offset:128" : "=v"(va1) : "v"(vtb0));
        asm volatile("ds_read_b64_tr_b16 %0, %1 offset:256" : "=v"(va2) : "v"(vtb0));
        asm volatile("ds_read_b64_tr_b16 %0, %1 offset:384" : "=v"(va3) : "v"(vtb0));
        asm volatile("s_waitcnt lgkmcnt(0)" ::: "memory");
        __builtin_amdgcn_sched_barrier(0);

        f32x4 sc[4] = {};
        __builtin_amdgcn_s_setprio(1);
#pragma unroll
        for (int qt = 0; qt < 4; ++qt)
            sc[qt] = __builtin_amdgcn_mfma_f32_16x16x32_bf16(kf0, qf[qt][0], sc[qt], 0, 0, 0);
#pragma unroll
        for (int qt = 0; qt < 4; ++qt)
            sc[qt] = __builtin_amdgcn_mfma_f32_16x16x32_bf16(kf1, qf[qt][1], sc[qt], 0, 0, 0);
        __builtin_amdgcn_s_setprio(0);
        if (more) STAGE(0, (2 * i2 + 2) * 64)

        unsigned u01[4], u23[4];
#pragma unroll
        for (int qt = 0; qt < 4; ++qt) {
            float p0 = fx2(sc[qt][0]), p1 = fx2(sc[qt][1]);
            float p2 = fx2(sc[qt][2]), p3 = fx2(sc[qt][3]);
            lr[qt] += (p0 + p1) + (p2 + p3);
            u01[qt] = pk2(p0, p1); u23[qt] = pk2(p2, p3);
        }

        if (more) { asm volatile("s_waitcnt vmcnt(4)" ::: "memory"); }
        else      { asm volatile("s_waitcnt vmcnt(0)" ::: "memory"); }
        s16x8 kg0 = *reinterpret_cast<const s16x8*>(wbase + 4096 + kro0);
        s16x8 kg1 = *reinterpret_cast<const s16x8*>(wbase + 4096 + kro1);
        s16x4 vb0, vb1, vb2, vb3;
        const unsigned vtb1 = vtb0 + 4096;
        asm volatile("ds_read_b64_tr_b16 %0, %1"            : "=v"(vb0) : "v"(vtb1));
        asm volatile("ds_read_b64_tr_b16 %0, %1 offset:128" : "=v"(vb1) : "v"(vtb1));
        asm volatile("ds_read_b64_tr_b16 %0, %1 offset:256" : "=v"(vb2) : "v"(vtb1));
        asm volatile("ds_read_b64_tr_b16 %0, %1 offset:384" : "=v"(vb3) : "v"(vtb1));
        asm volatile("s_waitcnt lgkmcnt(0)" ::: "memory");
        __builtin_amdgcn_sched_barrier(0);

        f32x4 sd[4] = {};
        __builtin_amdgcn_s_setprio(1);
#pragma unroll
        for (int qt = 0; qt < 4; ++qt)
            sd[qt] = __builtin_amdgcn_mfma_f32_16x16x32_bf16(kg0, qf[qt][0], sd[qt], 0, 0, 0);
#pragma unroll
        for (int qt = 0; qt < 4; ++qt)
            sd[qt] = __builtin_amdgcn_mfma_f32_16x16x32_bf16(kg1, qf[qt][1], sd[qt], 0, 0, 0);
        __builtin_amdgcn_s_setprio(0);
        if (more) STAGE(1, (2 * i2 + 3) * 64)

        s16x8 pf8[4];
#pragma unroll
        for (int qt = 0; qt < 4; ++qt) {
            float p0 = fx2(sd[qt][0]), p1 = fx2(sd[qt][1]);
            float p2 = fx2(sd[qt][2]), p3 = fx2(sd[qt][3]);
            lr[qt] += (p0 + p1) + (p2 + p3);
            pf8[qt] = mk8(u01[qt], u23[qt], pk2(p0, p1), pk2(p2, p3));
        }
        s16x8 vf80 = cat8(va0, vb0), vf81 = cat8(va1, vb1);
        s16x8 vf82 = cat8(va2, vb2), vf83 = cat8(va3, vb3);

        __builtin_amdgcn_s_setprio(1);
#pragma unroll
        for (int qt = 0; qt < 4; ++qt) {
            od[0][qt] = __builtin_amdgcn_mfma_f32_16x16x32_bf16(vf80, pf8[qt], od[0][qt], 0, 0, 0);
            od[1][qt] = __builtin_amdgcn_mfma_f32_16x16x32_bf16(vf81, pf8[qt], od[1][qt], 0, 0, 0);
            od[2][qt] = __builtin_amdgcn_mfma_f32_16x16x32_bf16(vf82, pf8[qt], od[2][qt], 0, 0, 0);
            od[3][qt] = __builtin_amdgcn_mfma_f32_16x16x32_bf16(vf83, pf8[qt], od[3][qt], 0, 0, 0);
        }
        __builtin_amdgcn_s_setprio(0);
    }
#undef STAGE

#pragma unroll
    for (int qt = 0; qt < 4; ++qt) {
        lr[qt] += __shfl_xor(lr[qt], 16);
        lr[qt] += __shfl_xor(lr[qt], 32);
    }
    __syncthreads();
    float* red = reinterpret_cast<float*>(smem);
    float* ldl = reinterpret_cast<float*>(smem + 32768);
    if (lane < 16) {
#pragma unroll
        for (int qt = 0; qt < 4; ++qt) ldl[w * 64 + qt * 16 + lane] = lr[qt];
    }

    const int b = bh >> 4, h = bh & 15;
    const int ql = w * 16 + (lane >> 2);
    const int qc = ql & 7;
    float linv = 0.f;
#pragma unroll
    for (int p = 0; p < 2; ++p) {
        if (p) __syncthreads();
#pragma unroll
        for (int dtp = 0; dtp < 2; ++dtp) {
#pragma unroll
            for (int qt = 0; qt < 4; ++qt) {
                int q = qt * 16 + lo;
                int quad = ((dtp << 2) + hi) ^ (lo & 7);
                *reinterpret_cast<f32x4*>(red + w * 2048 + q * 32 + quad * 4) = od[p * 2 + dtp][qt];
            }
        }
        __syncthreads();
        float s0[8] = {0.f, 0.f, 0.f, 0.f, 0.f, 0.f, 0.f, 0.f};
#pragma unroll
        for (int w2 = 0; w2 < 4; ++w2)
#pragma unroll
            for (int k = 0; k < 2; ++k) {
                int quad = (((lane & 3) << 1) + k) ^ qc;
                f32x4 v = *reinterpret_cast<const f32x4*>(red + w2 * 2048 + ql * 32 + quad * 4);
#pragma unroll
                for (int j = 0; j < 4; ++j) s0[k * 4 + j] += v[j];
            }
        if (p == 0)
            linv = 1.f / (ldl[ql] + ldl[64 + ql] + ldl[128 + ql] + ldl[192 + ql]);
        unsigned uu[4];
#pragma unroll
        for (int k2 = 0; k2 < 4; ++k2)
            uu[k2] = pk2(s0[2 * k2] * linv, s0[2 * k2 + 1] * linv);
        int4 ov;
        ov.x = uu[0]; ov.y = uu[1]; ov.z = uu[2]; ov.w = uu[3];
        *reinterpret_cast<int4*>(ao + ((long)(b * SEQ + q0 + ql)) * DIM +
                                 h * 64 + p * 32 + (lane & 3) * 8) = ov;
    }
}

extern "C" void kernel_launch(void* const* d_in, const int* in_sizes, int n_in,
                              void* d_out, int out_size, void* d_ws, size_t ws_size,
                              hipStream_t stream) {
    const float* x   = (const float*)d_in[0];
    const float* wq  = (const float*)d_in[1];
    const float* wk  = (const float*)d_in[2];
    const float* wv  = (const float*)d_in[3];
    const float* wo  = (const float*)d_in[4];
    const float* wob = (const float*)d_in[5];

    char* ws = (char*)d_ws;
    unsigned short* xb   = (unsigned short*)(ws);             // 8.0 MiB
    unsigned short* wqkv = (unsigned short*)(ws + 8388608);   // 6.0 MiB
    unsigned short* wwo  = (unsigned short*)(ws + 14680064);  // 2.0 MiB
    unsigned short* qw   = (unsigned short*)(ws + 16777216);  // 8.0 MiB
    unsigned short* kw   = (unsigned short*)(ws + 25165824);  // 8.0 MiB
    unsigned short* vw   = (unsigned short*)(ws + 33554432);  // 8.0 MiB
    unsigned short* ao   = (unsigned short*)(ws + 41943040);  // 8.0 MiB
    float2* tab          = (float2*)(ws + 50331648);          // 512 KiB

    prep_kernel<<<8448, 256, 0, stream>>>(x, wq, wk, wv, wo, xb, wqkv, wwo, tab);

    // gemm0: 24 x-tiles x 32 y-tiles (128x128) = 768 multi-wave blocks
    gemm_mw<0><<<768, 256, 0, stream>>>(xb, wqkv, tab, qw, kw, vw, nullptr, nullptr);
    flash_attn<<<1024, 256, 0, stream>>>(qw, kw, vw, ao);
    // gemm1: 8 x-tiles x 64 y-tiles = 512 one-wave blocks (r14)
    gemm_async<1><<<512, 64, 0, stream>>>(ao, wwo, nullptr, nullptr, nullptr, nullptr,
                                          (float*)d_out, wob);
}